// Round 16
// baseline (1132.847 us; speedup 1.0000x reference)
//
#include <hip/hip_runtime.h>

#define NTOK 49
#define HEADS 6
#define CDIM 192
#define NWIN 4096

typedef unsigned short u16;
typedef unsigned int u32;
typedef unsigned long long u64;
typedef __attribute__((ext_vector_type(8))) __bf16 bf16x8;
typedef __attribute__((ext_vector_type(4))) float floatx4;
typedef __attribute__((ext_vector_type(4))) u32 u32x4;

struct __attribute__((aligned(4))) F4 { float f[4]; };

// LDS layout (bytes), 16-wave block (1024 thr), 1 block/CU.
#define OFF_X 0         // [64][200] u16 (AO only; X never staged)  25600
#define OFF_Q 25600     // [64][200] u16 (raw Q)                    25600
#define OFF_K 51200     // [64][200] u16 (raw K)                    25600
#define OFF_V 76800     // [192][72] u16  Vt[chan][tok]             27648
#define OFF_N 104448    // [16 waves][128] f32 (krec|qrec)           8192
#define OFF_NP 112640   // [2][12][64] f32 partial sumsq             6144
#define LDS_BYTES 118784

// HW bf16 convert (RNE).
__device__ __forceinline__ u16 f2bf(float f) {
  return __builtin_bit_cast(u16, (__bf16)f);
}
__device__ __forceinline__ void st4bf(u16* p, float a, float b, float c, float d) {
  u32 lo = (u32)f2bf(a) | ((u32)f2bf(b) << 16);
  u32 hi = (u32)f2bf(c) | ((u32)f2bf(d) << 16);
  u64 t = (u64)lo | ((u64)hi << 32);
  *(u64*)p = t;
}
__device__ __forceinline__ u32 pack2bf(float lo, float hi) {
  return (u32)f2bf(lo) | ((u32)f2bf(hi) << 16);
}
__device__ __forceinline__ bf16x8 frag_from_words(u32 a, u32 b, u32 c, u32 d) {
  u32x4 t = {a, b, c, d};
  return __builtin_bit_cast(bf16x8, t);
}

__global__ __launch_bounds__(256)
void wprep(const float* __restrict__ Wq, const float* __restrict__ Wk,
           const float* __restrict__ Wv, const float* __restrict__ Wp,
           const float* __restrict__ rpb, const int* __restrict__ rel,
           u16* __restrict__ w_bf, float* __restrict__ bias) {
  const int tid = blockIdx.x * blockDim.x + threadIdx.x;
  const int stride = gridDim.x * blockDim.x;
  for (int i = tid; i < 4 * CDIM * CDIM; i += stride) {
    const int p = i / (CDIM * CDIM), e = i % (CDIM * CDIM);
    float v = (p == 0) ? Wq[e] : (p == 1) ? Wk[e] : (p == 2) ? Wv[e] : Wp[e];
    w_bf[i] = f2bf(v);
  }
  for (int i = tid; i < HEADS * NTOK * NTOK; i += stride) {
    const int h = i / (NTOK * NTOK), nm = i % (NTOK * NTOK);
    bias[i] = rpb[rel[nm] * HEADS + h];
  }
}

// Fused window attention: R14 structure, phase 0 deleted (x fragments built
// directly from global, R4-k1-proven pattern), phase-3 double-tasks moved to
// waves 8-15 (which carry fewer phase-1 tasks). 2 barriers total.
__global__ __launch_bounds__(1024)
void wattn_main(const float* __restrict__ x, const float* __restrict__ mask,
                const float* __restrict__ d_l, const float* __restrict__ temp,
                const u16* __restrict__ w_bf, const float* __restrict__ bias,
                float* __restrict__ out) {
  extern __shared__ __align__(16) char smem[];
  u16* Xb = (u16*)(smem + OFF_X);   // AO
  u16* Qn = (u16*)(smem + OFF_Q);
  u16* Kn = (u16*)(smem + OFF_K);
  u16* Vt = (u16*)(smem + OFF_V);
  float* NP = (float*)(smem + OFF_NP);  // [2][12][64] partial sumsq (p: 0=Q,1=K)

  const int b = blockIdx.x;
  const int tid = threadIdx.x;
  const int wave = tid >> 6;   // 0..15
  const int lane = tid & 63;
  const int g = lane >> 4;
  const int nl = lane & 15;

  // ---- phase 1: QKV, 36 tasks over 16 waves; x fragments direct from global
  //      (f32->bf16 pack; zero for tok>=49). Q/K tasks emit f32 sumsq partials.
  {
    const float* xw = x + (size_t)b * (NTOK * CDIM);
    for (int u = wave; u < 36; u += 16) {
      const int p = u / 12, o = u % 12;
      const u16* wb = w_bf + p * (CDIM * CDIM) + (o * 16 + nl) * CDIM + g * 8;
      floatx4 acc[4];
#pragma unroll
      for (int nt = 0; nt < 4; ++nt) acc[nt] = (floatx4){0.f, 0.f, 0.f, 0.f};
#pragma unroll
      for (int k = 0; k < 6; ++k) {
        const bf16x8 wf = *(const bf16x8*)(wb + k * 32);
#pragma unroll
        for (int nt = 0; nt < 4; ++nt) {
          const int tok = nt * 16 + nl;
          bf16x8 xk;
          if (tok < NTOK) {
            const float4 lo = *(const float4*)(xw + tok * CDIM + k * 32 + g * 8);
            const float4 hi = *(const float4*)(xw + tok * CDIM + k * 32 + g * 8 + 4);
            u32x4 t;
            t[0] = pack2bf(lo.x, lo.y); t[1] = pack2bf(lo.z, lo.w);
            t[2] = pack2bf(hi.x, hi.y); t[3] = pack2bf(hi.z, hi.w);
            xk = __builtin_bit_cast(bf16x8, t);
          } else {
            u32x4 t = {0u, 0u, 0u, 0u};
            xk = __builtin_bit_cast(bf16x8, t);
          }
          if (p < 2)
            acc[nt] = __builtin_amdgcn_mfma_f32_16x16x32_bf16(wf, xk, acc[nt], 0, 0, 0);
          else
            acc[nt] = __builtin_amdgcn_mfma_f32_16x16x32_bf16(xk, wf, acc[nt], 0, 0, 0);
        }
      }
      if (p < 2) {
        u16* dst = (p == 0 ? Qn : Kn);
        float* np = NP + (p * 12 + o) * 64;
#pragma unroll
        for (int nt = 0; nt < 4; ++nt) {
          st4bf(dst + (nt * 16 + nl) * 200 + o * 16 + g * 4,
                acc[nt][0], acc[nt][1], acc[nt][2], acc[nt][3]);
          float s = acc[nt][0] * acc[nt][0];
          s = fmaf(acc[nt][1], acc[nt][1], s);
          s = fmaf(acc[nt][2], acc[nt][2], s);
          s = fmaf(acc[nt][3], acc[nt][3], s);
          s += __shfl_xor(s, 16);
          s += __shfl_xor(s, 32);
          if (g == 0) np[nt * 16 + nl] = s;
        }
      } else {
#pragma unroll
        for (int nt = 0; nt < 4; ++nt)
          st4bf(Vt + (o * 16 + nl) * 72 + nt * 16 + g * 4,
                acc[nt][0], acc[nt][1], acc[nt][2], acc[nt][3]);
      }
    }
  }
  __syncthreads();

  // ---- phase 3: attention; folded norm, no max-subtraction, in-register P exchange.
  //      Waves 8-15: t={2(w-8), 2(w-8)+1} (double); waves 0-7: t={w+16} (single).
  {
    const float dl = d_l[b];
    const float LOG2E = 1.442695040888963f;
    const float dl2 = dl * LOG2E;
    const int wmask = b & (NWIN - 1);
    float* nrmw = (float*)(smem + OFF_N) + wave * 128;
    const int srcA = nl + ((lane & 16) << 1);  // nl + 32*(g&1)
    const int srcB = srcA + 16;
    const bool hsel = (g >> 1) != 0;

    int t0, ntask;
    if (wave >= 8) { t0 = (wave - 8) * 2; ntask = 2; }
    else           { t0 = wave + 16; ntask = 1; }
    const int h = t0 >> 2;

    // combine partials -> reciprocal norms (lane = token; coalesced f32 reads)
    {
      const float kss = NP[(12 + 2 * h) * 64 + lane] + NP[(12 + 2 * h + 1) * 64 + lane];
      const float qss = NP[(2 * h) * 64 + lane] + NP[(2 * h + 1) * 64 + lane];
      nrmw[lane] = 1.f / fmaxf(sqrtf(kss), 1e-12f);
      nrmw[64 + lane] = 1.f / fmaxf(sqrtf(qss), 1e-12f);
    }

    const float tdl = temp[h] * dl2;
    bf16x8 kf[4];
#pragma unroll
    for (int rt = 0; rt < 4; ++rt)
      kf[rt] = *(const bf16x8*)(Kn + (rt * 16 + nl) * 200 + h * 32 + g * 8);

    for (int j = 0; j < ntask; ++j) {
      const int t = t0 + j;
      const int nt2 = t & 3;
      const int n = nt2 * 16 + nl;
      const int ncl = n < NTOK ? n : NTOK - 1;
      const bf16x8 qf = *(const bf16x8*)(Qn + n * 200 + h * 32 + g * 8);
      floatx4 sacc[4];
#pragma unroll
      for (int rt = 0; rt < 4; ++rt)
        sacc[rt] = __builtin_amdgcn_mfma_f32_16x16x32_bf16(kf[rt], qf, (floatx4){0.f, 0.f, 0.f, 0.f}, 0, 0, 0);
      const float qr2 = nrmw[64 + n] * tdl;
      const float* brow = bias + (h * NTOK + ncl) * NTOK;
      const float* mrow = mask + ((size_t)wmask * NTOK + ncl) * NTOK;
      float L[4][4];
#pragma unroll
      for (int rt = 0; rt < 3; ++rt) {
        const F4 b4 = *(const F4*)(brow + rt * 16 + g * 4);
        const F4 m4 = *(const F4*)(mrow + rt * 16 + g * 4);
        const F4 kr = *(const F4*)(nrmw + rt * 16 + g * 4);
#pragma unroll
        for (int r = 0; r < 4; ++r)
          L[rt][r] = fmaf(sacc[rt][r] * kr.f[r], qr2, (b4.f[r] + m4.f[r]) * dl2);
      }
      {  // rt=3: only m=48 real (g==0, r==0)
        const float lv48 = fmaf(sacc[3][0] * nrmw[48], qr2, (brow[48] + mrow[48]) * dl2);
        L[3][0] = L[3][1] = L[3][2] = L[3][3] = -1e30f;
        if (g == 0) L[3][0] = lv48;
      }
      float psum = 0.f;
#pragma unroll
      for (int rt = 0; rt < 4; ++rt)
#pragma unroll
        for (int r = 0; r < 4; ++r) {
          const float e = exp2f(L[rt][r]);
          L[rt][r] = e;
          psum += e;
        }
      psum += __shfl_xor(psum, 16);
      psum += __shfl_xor(psum, 32);
      const float rinv = 1.0f / psum;

      // in-register P -> B-fragment exchange (R3/R14-proven)
      u32 pk[4][2];
#pragma unroll
      for (int rt = 0; rt < 4; ++rt)
#pragma unroll
        for (int w2 = 0; w2 < 2; ++w2)
          pk[rt][w2] = pack2bf(L[rt][2 * w2] * rinv, L[rt][2 * w2 + 1] * rinv);
      u32 pf[2][4];
#pragma unroll
      for (int ks = 0; ks < 2; ++ks) {
        const u32 a0 = __shfl((int)pk[2 * ks][0], srcA), b0 = __shfl((int)pk[2 * ks + 1][0], srcA);
        const u32 a1 = __shfl((int)pk[2 * ks][1], srcA), b1 = __shfl((int)pk[2 * ks + 1][1], srcA);
        const u32 a2 = __shfl((int)pk[2 * ks][0], srcB), b2 = __shfl((int)pk[2 * ks + 1][0], srcB);
        const u32 a3 = __shfl((int)pk[2 * ks][1], srcB), b3 = __shfl((int)pk[2 * ks + 1][1], srcB);
        pf[ks][0] = hsel ? b0 : a0;
        pf[ks][1] = hsel ? b1 : a1;
        pf[ks][2] = hsel ? b2 : a2;
        pf[ks][3] = hsel ? b3 : a3;
      }

      floatx4 oacc[2];
      oacc[0] = (floatx4){0.f, 0.f, 0.f, 0.f};
      oacc[1] = (floatx4){0.f, 0.f, 0.f, 0.f};
#pragma unroll
      for (int ks = 0; ks < 2; ++ks) {
        const bf16x8 pfr = frag_from_words(pf[ks][0], pf[ks][1], pf[ks][2], pf[ks][3]);
#pragma unroll
        for (int dt = 0; dt < 2; ++dt) {
          const bf16x8 vf = *(const bf16x8*)(Vt + (h * 32 + dt * 16 + nl) * 72 + ks * 32 + g * 8);
          oacc[dt] = __builtin_amdgcn_mfma_f32_16x16x32_bf16(vf, pfr, oacc[dt], 0, 0, 0);
        }
      }
#pragma unroll
      for (int dt = 0; dt < 2; ++dt)
        st4bf(Xb + n * 200 + h * 32 + dt * 16 + g * 4,
              oacc[dt][0], oacc[dt][1], oacc[dt][2], oacc[dt][3]);
    }
  }
  __syncthreads();

  // ---- phase 4: out = AO @ Wp^T (out^T = Wp * AO^T), 12 tasks over 16 waves
  {
    float* outb = out + (size_t)b * (NTOK * CDIM);
    const u16* wpb = w_bf + 3 * (CDIM * CDIM);
    for (int o = wave; o < 12; o += 16) {
      const u16* wb = wpb + (o * 16 + nl) * CDIM + g * 8;
      floatx4 acc[4];
#pragma unroll
      for (int nt = 0; nt < 4; ++nt) acc[nt] = (floatx4){0.f, 0.f, 0.f, 0.f};
#pragma unroll
      for (int k = 0; k < 6; ++k) {
        const bf16x8 wf = *(const bf16x8*)(wb + k * 32);
#pragma unroll
        for (int nt = 0; nt < 4; ++nt) {
          const bf16x8 af = *(const bf16x8*)(Xb + (nt * 16 + nl) * 200 + k * 32 + g * 8);
          acc[nt] = __builtin_amdgcn_mfma_f32_16x16x32_bf16(wf, af, acc[nt], 0, 0, 0);
        }
      }
#pragma unroll
      for (int nt = 0; nt < 4; ++nt) {
        const int n = nt * 16 + nl;
        if (n < NTOK) {
          float4 v;
          v.x = acc[nt][0]; v.y = acc[nt][1]; v.z = acc[nt][2]; v.w = acc[nt][3];
          *(float4*)(outb + n * CDIM + o * 16 + g * 4) = v;
        }
      }
    }
  }
}

extern "C" void kernel_launch(void* const* d_in, const int* in_sizes, int n_in,
                              void* d_out, int out_size, void* d_ws, size_t ws_size,
                              hipStream_t stream) {
  const float* x    = (const float*)d_in[0];
  const float* mask = (const float*)d_in[1];
  const float* dl   = (const float*)d_in[2];
  const float* Wq   = (const float*)d_in[3];
  const float* Wk   = (const float*)d_in[4];
  const float* Wv   = (const float*)d_in[5];
  const float* Wp   = (const float*)d_in[6];
  const float* temp = (const float*)d_in[7];
  const float* rpb  = (const float*)d_in[8];
  const int*   rel  = (const int*)d_in[9];

  u16* w_bf = (u16*)d_ws;
  float* bias = (float*)((char*)d_ws + (size_t)4 * CDIM * CDIM * sizeof(u16));
  float* o = (float*)d_out;

  (void)hipFuncSetAttribute((const void*)wattn_main,
                            hipFuncAttributeMaxDynamicSharedMemorySize, LDS_BYTES);

  wprep<<<256, 256, 0, stream>>>(Wq, Wk, Wv, Wp, rpb, rel, w_bf, bias);
  wattn_main<<<8192, 1024, LDS_BYTES, stream>>>(x, mask, dl, temp, w_bf, bias, o);
}

// Round 17
// 545.658 us; speedup vs baseline: 2.0761x; 2.0761x over previous
//
#include <hip/hip_runtime.h>

#define NTOK 49
#define HEADS 6
#define CDIM 192
#define NWIN 4096

typedef unsigned short u16;
typedef unsigned int u32;
typedef unsigned long long u64;
typedef __attribute__((ext_vector_type(8))) __bf16 bf16x8;
typedef __attribute__((ext_vector_type(4))) float floatx4;
typedef __attribute__((ext_vector_type(4))) u32 u32x4;

struct __attribute__((aligned(4))) F4 { float f[4]; };

// LDS layout (bytes), 16-wave block (1024 thr), 1 block/CU. P slab eliminated (in-reg).
#define OFF_X 0         // [64][200] u16 (X, later AO)          25600
#define OFF_Q 25600     // [64][200] u16 (raw Q)                25600
#define OFF_K 51200     // [64][200] u16 (raw K)                25600
#define OFF_V 76800     // [192][72] u16  Vt[chan][tok]         27648
#define OFF_N 104448    // [16 waves][128] f32 (krec|qrec)       8192
#define OFF_NP 112640   // [2][12][64] f32 partial sumsq         6144
#define LDS_BYTES 118784

// HW bf16 convert (RNE).
__device__ __forceinline__ u16 f2bf(float f) {
  return __builtin_bit_cast(u16, (__bf16)f);
}
__device__ __forceinline__ void st4bf(u16* p, float a, float b, float c, float d) {
  u32 lo = (u32)f2bf(a) | ((u32)f2bf(b) << 16);
  u32 hi = (u32)f2bf(c) | ((u32)f2bf(d) << 16);
  u64 t = (u64)lo | ((u64)hi << 32);
  *(u64*)p = t;
}
__device__ __forceinline__ u32 pack2bf(float lo, float hi) {
  return (u32)f2bf(lo) | ((u32)f2bf(hi) << 16);
}
__device__ __forceinline__ bf16x8 frag_from_words(u32 a, u32 b, u32 c, u32 d) {
  u32x4 t = {a, b, c, d};
  return __builtin_bit_cast(bf16x8, t);
}

__global__ __launch_bounds__(256)
void wprep(const float* __restrict__ Wq, const float* __restrict__ Wk,
           const float* __restrict__ Wv, const float* __restrict__ Wp,
           const float* __restrict__ rpb, const int* __restrict__ rel,
           u16* __restrict__ w_bf, float* __restrict__ bias) {
  const int tid = blockIdx.x * blockDim.x + threadIdx.x;
  const int stride = gridDim.x * blockDim.x;
  for (int i = tid; i < 4 * CDIM * CDIM; i += stride) {
    const int p = i / (CDIM * CDIM), e = i % (CDIM * CDIM);
    float v = (p == 0) ? Wq[e] : (p == 1) ? Wk[e] : (p == 2) ? Wv[e] : Wp[e];
    w_bf[i] = f2bf(v);
  }
  for (int i = tid; i < HEADS * NTOK * NTOK; i += stride) {
    const int h = i / (NTOK * NTOK), nm = i % (NTOK * NTOK);
    bias[i] = rpb[rel[nm] * HEADS + h];
  }
}

// Fused window attention: R14 verbatim except phase-3 double-tasks moved to
// waves 8-15 (waves 0-3 carry 3 phase-1 tasks; flattens worst-case wave load).
__global__ __launch_bounds__(1024)
void wattn_main(const float* __restrict__ x, const float* __restrict__ mask,
                const float* __restrict__ d_l, const float* __restrict__ temp,
                const u16* __restrict__ w_bf, const float* __restrict__ bias,
                float* __restrict__ out) {
  extern __shared__ __align__(16) char smem[];
  u16* Xb = (u16*)(smem + OFF_X);
  u16* Qn = (u16*)(smem + OFF_Q);
  u16* Kn = (u16*)(smem + OFF_K);
  u16* Vt = (u16*)(smem + OFF_V);
  float* NP = (float*)(smem + OFF_NP);  // [2][12][64] partial sumsq (p: 0=Q,1=K)

  const int b = blockIdx.x;
  const int tid = threadIdx.x;
  const int wave = tid >> 6;   // 0..15
  const int lane = tid & 63;
  const int g = lane >> 4;
  const int nl = lane & 15;

  // ---- phase 0: stage x -> bf16 LDS [64][200], zero pad rows 49..63
  {
    const float* xb = x + (size_t)b * (NTOK * CDIM);
    for (int i = tid; i < NTOK * 48; i += 1024) {
      const int n = i / 48;
      const int c = (i - n * 48) * 4;
      const float4 v = *(const float4*)(xb + n * CDIM + c);
      st4bf(Xb + n * 200 + c, v.x, v.y, v.z, v.w);
    }
    if (tid < 15 * 48) {
      const int n = NTOK + tid / 48;
      const int c = (tid % 48) * 4;
      *(u64*)(Xb + n * 200 + c) = 0ull;
    }
  }
  __syncthreads();

  // ---- phase 1: QKV, 36 tasks over 16 waves; Q/K tasks also emit f32 sumsq partials
  for (int u = wave; u < 36; u += 16) {
    const int p = u / 12, o = u % 12;
    const u16* wb = w_bf + p * (CDIM * CDIM) + (o * 16 + nl) * CDIM + g * 8;
    floatx4 acc[4];
#pragma unroll
    for (int nt = 0; nt < 4; ++nt) acc[nt] = (floatx4){0.f, 0.f, 0.f, 0.f};
    if (p < 2) {
#pragma unroll
      for (int k = 0; k < 6; ++k) {
        const bf16x8 wf = *(const bf16x8*)(wb + k * 32);
#pragma unroll
        for (int nt = 0; nt < 4; ++nt) {
          const bf16x8 xk = *(const bf16x8*)(Xb + (nt * 16 + nl) * 200 + k * 32 + g * 8);
          acc[nt] = __builtin_amdgcn_mfma_f32_16x16x32_bf16(wf, xk, acc[nt], 0, 0, 0);
        }
      }
      u16* dst = (p == 0 ? Qn : Kn);
      float* np = NP + (p * 12 + o) * 64;
#pragma unroll
      for (int nt = 0; nt < 4; ++nt) {
        st4bf(dst + (nt * 16 + nl) * 200 + o * 16 + g * 4,
              acc[nt][0], acc[nt][1], acc[nt][2], acc[nt][3]);
        float s = acc[nt][0] * acc[nt][0];
        s = fmaf(acc[nt][1], acc[nt][1], s);
        s = fmaf(acc[nt][2], acc[nt][2], s);
        s = fmaf(acc[nt][3], acc[nt][3], s);
        s += __shfl_xor(s, 16);
        s += __shfl_xor(s, 32);
        if (g == 0) np[nt * 16 + nl] = s;
      }
    } else {
#pragma unroll
      for (int k = 0; k < 6; ++k) {
        const bf16x8 wf = *(const bf16x8*)(wb + k * 32);
#pragma unroll
        for (int nt = 0; nt < 4; ++nt) {
          const bf16x8 xk = *(const bf16x8*)(Xb + (nt * 16 + nl) * 200 + k * 32 + g * 8);
          acc[nt] = __builtin_amdgcn_mfma_f32_16x16x32_bf16(xk, wf, acc[nt], 0, 0, 0);
        }
      }
#pragma unroll
      for (int nt = 0; nt < 4; ++nt)
        st4bf(Vt + (o * 16 + nl) * 72 + nt * 16 + g * 4,
              acc[nt][0], acc[nt][1], acc[nt][2], acc[nt][3]);
    }
  }
  __syncthreads();

  // ---- phase 3: attention; folded norm, no max-subtraction, in-register P exchange.
  //      Waves 8-15: t={2(w-8), 2(w-8)+1} (double); waves 0-7: t={w+16} (single).
  {
    const float dl = d_l[b];
    const float LOG2E = 1.442695040888963f;
    const float dl2 = dl * LOG2E;
    const int wmask = b & (NWIN - 1);
    float* nrmw = (float*)(smem + OFF_N) + wave * 128;
    const int srcA = nl + ((lane & 16) << 1);  // nl + 32*(g&1)
    const int srcB = srcA + 16;
    const bool hsel = (g >> 1) != 0;

    int t0, ntask;
    if (wave >= 8) { t0 = (wave - 8) * 2; ntask = 2; }
    else           { t0 = wave + 16; ntask = 1; }
    const int h = t0 >> 2;

    // combine partials -> reciprocal norms (lane = token; coalesced f32 reads)
    {
      const float kss = NP[(12 + 2 * h) * 64 + lane] + NP[(12 + 2 * h + 1) * 64 + lane];
      const float qss = NP[(2 * h) * 64 + lane] + NP[(2 * h + 1) * 64 + lane];
      nrmw[lane] = 1.f / fmaxf(sqrtf(kss), 1e-12f);
      nrmw[64 + lane] = 1.f / fmaxf(sqrtf(qss), 1e-12f);
    }

    const float tdl = temp[h] * dl2;
    bf16x8 kf[4];
#pragma unroll
    for (int rt = 0; rt < 4; ++rt)
      kf[rt] = *(const bf16x8*)(Kn + (rt * 16 + nl) * 200 + h * 32 + g * 8);

    for (int j = 0; j < ntask; ++j) {
      const int t = t0 + j;
      const int nt2 = t & 3;
      const int n = nt2 * 16 + nl;
      const int ncl = n < NTOK ? n : NTOK - 1;
      const bf16x8 qf = *(const bf16x8*)(Qn + n * 200 + h * 32 + g * 8);
      floatx4 sacc[4];
#pragma unroll
      for (int rt = 0; rt < 4; ++rt)
        sacc[rt] = __builtin_amdgcn_mfma_f32_16x16x32_bf16(kf[rt], qf, (floatx4){0.f, 0.f, 0.f, 0.f}, 0, 0, 0);
      const float qr2 = nrmw[64 + n] * tdl;
      const float* brow = bias + (h * NTOK + ncl) * NTOK;
      const float* mrow = mask + ((size_t)wmask * NTOK + ncl) * NTOK;
      float L[4][4];
#pragma unroll
      for (int rt = 0; rt < 3; ++rt) {
        const F4 b4 = *(const F4*)(brow + rt * 16 + g * 4);
        const F4 m4 = *(const F4*)(mrow + rt * 16 + g * 4);
        const F4 kr = *(const F4*)(nrmw + rt * 16 + g * 4);
#pragma unroll
        for (int r = 0; r < 4; ++r)
          L[rt][r] = fmaf(sacc[rt][r] * kr.f[r], qr2, (b4.f[r] + m4.f[r]) * dl2);
      }
      {  // rt=3: only m=48 real (g==0, r==0)
        const float lv48 = fmaf(sacc[3][0] * nrmw[48], qr2, (brow[48] + mrow[48]) * dl2);
        L[3][0] = L[3][1] = L[3][2] = L[3][3] = -1e30f;
        if (g == 0) L[3][0] = lv48;
      }
      float psum = 0.f;
#pragma unroll
      for (int rt = 0; rt < 4; ++rt)
#pragma unroll
        for (int r = 0; r < 4; ++r) {
          const float e = exp2f(L[rt][r]);
          L[rt][r] = e;
          psum += e;
        }
      psum += __shfl_xor(psum, 16);
      psum += __shfl_xor(psum, 32);
      const float rinv = 1.0f / psum;

      // in-register P -> B-fragment exchange (R3/R14-proven)
      u32 pk[4][2];
#pragma unroll
      for (int rt = 0; rt < 4; ++rt)
#pragma unroll
        for (int w2 = 0; w2 < 2; ++w2)
          pk[rt][w2] = pack2bf(L[rt][2 * w2] * rinv, L[rt][2 * w2 + 1] * rinv);
      u32 pf[2][4];
#pragma unroll
      for (int ks = 0; ks < 2; ++ks) {
        const u32 a0 = __shfl((int)pk[2 * ks][0], srcA), b0 = __shfl((int)pk[2 * ks + 1][0], srcA);
        const u32 a1 = __shfl((int)pk[2 * ks][1], srcA), b1 = __shfl((int)pk[2 * ks + 1][1], srcA);
        const u32 a2 = __shfl((int)pk[2 * ks][0], srcB), b2 = __shfl((int)pk[2 * ks + 1][0], srcB);
        const u32 a3 = __shfl((int)pk[2 * ks][1], srcB), b3 = __shfl((int)pk[2 * ks + 1][1], srcB);
        pf[ks][0] = hsel ? b0 : a0;
        pf[ks][1] = hsel ? b1 : a1;
        pf[ks][2] = hsel ? b2 : a2;
        pf[ks][3] = hsel ? b3 : a3;
      }

      floatx4 oacc[2];
      oacc[0] = (floatx4){0.f, 0.f, 0.f, 0.f};
      oacc[1] = (floatx4){0.f, 0.f, 0.f, 0.f};
#pragma unroll
      for (int ks = 0; ks < 2; ++ks) {
        const bf16x8 pfr = frag_from_words(pf[ks][0], pf[ks][1], pf[ks][2], pf[ks][3]);
#pragma unroll
        for (int dt = 0; dt < 2; ++dt) {
          const bf16x8 vf = *(const bf16x8*)(Vt + (h * 32 + dt * 16 + nl) * 72 + ks * 32 + g * 8);
          oacc[dt] = __builtin_amdgcn_mfma_f32_16x16x32_bf16(vf, pfr, oacc[dt], 0, 0, 0);
        }
      }
#pragma unroll
      for (int dt = 0; dt < 2; ++dt)
        st4bf(Xb + n * 200 + h * 32 + dt * 16 + g * 4,
              oacc[dt][0], oacc[dt][1], oacc[dt][2], oacc[dt][3]);
    }
  }
  __syncthreads();

  // ---- phase 4: out = AO @ Wp^T (out^T = Wp * AO^T), 12 tasks over 16 waves
  {
    float* outb = out + (size_t)b * (NTOK * CDIM);
    const u16* wpb = w_bf + 3 * (CDIM * CDIM);
    for (int o = wave; o < 12; o += 16) {
      const u16* wb = wpb + (o * 16 + nl) * CDIM + g * 8;
      floatx4 acc[4];
#pragma unroll
      for (int nt = 0; nt < 4; ++nt) acc[nt] = (floatx4){0.f, 0.f, 0.f, 0.f};
#pragma unroll
      for (int k = 0; k < 6; ++k) {
        const bf16x8 wf = *(const bf16x8*)(wb + k * 32);
#pragma unroll
        for (int nt = 0; nt < 4; ++nt) {
          const bf16x8 af = *(const bf16x8*)(Xb + (nt * 16 + nl) * 200 + k * 32 + g * 8);
          acc[nt] = __builtin_amdgcn_mfma_f32_16x16x32_bf16(wf, af, acc[nt], 0, 0, 0);
        }
      }
#pragma unroll
      for (int nt = 0; nt < 4; ++nt) {
        const int n = nt * 16 + nl;
        if (n < NTOK) {
          float4 v;
          v.x = acc[nt][0]; v.y = acc[nt][1]; v.z = acc[nt][2]; v.w = acc[nt][3];
          *(float4*)(outb + n * CDIM + o * 16 + g * 4) = v;
        }
      }
    }
  }
}

extern "C" void kernel_launch(void* const* d_in, const int* in_sizes, int n_in,
                              void* d_out, int out_size, void* d_ws, size_t ws_size,
                              hipStream_t stream) {
  const float* x    = (const float*)d_in[0];
  const float* mask = (const float*)d_in[1];
  const float* dl   = (const float*)d_in[2];
  const float* Wq   = (const float*)d_in[3];
  const float* Wk   = (const float*)d_in[4];
  const float* Wv   = (const float*)d_in[5];
  const float* Wp   = (const float*)d_in[6];
  const float* temp = (const float*)d_in[7];
  const float* rpb  = (const float*)d_in[8];
  const int*   rel  = (const int*)d_in[9];

  u16* w_bf = (u16*)d_ws;
  float* bias = (float*)((char*)d_ws + (size_t)4 * CDIM * CDIM * sizeof(u16));
  float* o = (float*)d_out;

  (void)hipFuncSetAttribute((const void*)wattn_main,
                            hipFuncAttributeMaxDynamicSharedMemorySize, LDS_BYTES);

  wprep<<<256, 256, 0, stream>>>(Wq, Wk, Wv, Wp, rpb, rel, w_bf, bias);
  wattn_main<<<8192, 1024, LDS_BYTES, stream>>>(x, mask, dl, temp, w_bf, bias, o);
}

// Round 18
// 531.206 us; speedup vs baseline: 2.1326x; 1.0272x over previous
//
#include <hip/hip_runtime.h>

#define NTOK 49
#define HEADS 6
#define CDIM 192
#define NWIN 4096

typedef unsigned short u16;
typedef unsigned int u32;
typedef unsigned long long u64;
typedef __attribute__((ext_vector_type(8))) __bf16 bf16x8;
typedef __attribute__((ext_vector_type(4))) float floatx4;
typedef __attribute__((ext_vector_type(4))) u32 u32x4;

struct __attribute__((aligned(4))) F4 { float f[4]; };

// LDS layout (bytes), 16-wave block (1024 thr), 1 block/CU. P slab eliminated (in-reg).
#define OFF_X 0         // [64][200] u16 (X, later AO)          25600
#define OFF_Q 25600     // [64][200] u16 (raw Q)                25600
#define OFF_K 51200     // [64][200] u16 (raw K)                25600
#define OFF_V 76800     // [192][72] u16  Vt[chan][tok]         27648
#define OFF_N 104448    // [16 waves][128] f32 (krec|qrec)       8192
#define OFF_NP 112640   // [2][12][64] f32 partial sumsq         6144
#define LDS_BYTES 118784

// HW bf16 convert (RNE).
__device__ __forceinline__ u16 f2bf(float f) {
  return __builtin_bit_cast(u16, (__bf16)f);
}
__device__ __forceinline__ void st4bf(u16* p, float a, float b, float c, float d) {
  u32 lo = (u32)f2bf(a) | ((u32)f2bf(b) << 16);
  u32 hi = (u32)f2bf(c) | ((u32)f2bf(d) << 16);
  u64 t = (u64)lo | ((u64)hi << 32);
  *(u64*)p = t;
}
__device__ __forceinline__ u32 pack2bf(float lo, float hi) {
  return (u32)f2bf(lo) | ((u32)f2bf(hi) << 16);
}
__device__ __forceinline__ bf16x8 frag_from_words(u32 a, u32 b, u32 c, u32 d) {
  u32x4 t = {a, b, c, d};
  return __builtin_bit_cast(bf16x8, t);
}

__global__ __launch_bounds__(256)
void wprep(const float* __restrict__ Wq, const float* __restrict__ Wk,
           const float* __restrict__ Wv, const float* __restrict__ Wp,
           const float* __restrict__ rpb, const int* __restrict__ rel,
           u16* __restrict__ w_bf, float* __restrict__ bias) {
  const int tid = blockIdx.x * blockDim.x + threadIdx.x;
  const int stride = gridDim.x * blockDim.x;
  for (int i = tid; i < 4 * CDIM * CDIM; i += stride) {
    const int p = i / (CDIM * CDIM), e = i % (CDIM * CDIM);
    float v = (p == 0) ? Wq[e] : (p == 1) ? Wk[e] : (p == 2) ? Wv[e] : Wp[e];
    w_bf[i] = f2bf(v);
  }
  for (int i = tid; i < HEADS * NTOK * NTOK; i += stride) {
    const int h = i / (NTOK * NTOK), nm = i % (NTOK * NTOK);
    bias[i] = rpb[rel[nm] * HEADS + h];
  }
}

// Fused window attention (best measured variant, = R14):
//  - 16 waves, 1 block/CU, 3 barriers
//  - phase 1: QKV GEMM, per-k fragment loads, f32 sumsq byproducts (norm fold)
//  - phase 3: folded l2-norm, exp2-domain softmax w/o max-subtraction,
//             in-register P->B-fragment exchange (no P LDS round-trip)
//  - phase 4: out-proj via transposed MFMA, coalesced float4 stores
__global__ __launch_bounds__(1024)
void wattn_main(const float* __restrict__ x, const float* __restrict__ mask,
                const float* __restrict__ d_l, const float* __restrict__ temp,
                const u16* __restrict__ w_bf, const float* __restrict__ bias,
                float* __restrict__ out) {
  extern __shared__ __align__(16) char smem[];
  u16* Xb = (u16*)(smem + OFF_X);
  u16* Qn = (u16*)(smem + OFF_Q);
  u16* Kn = (u16*)(smem + OFF_K);
  u16* Vt = (u16*)(smem + OFF_V);
  float* NP = (float*)(smem + OFF_NP);  // [2][12][64] partial sumsq (p: 0=Q,1=K)

  const int b = blockIdx.x;
  const int tid = threadIdx.x;
  const int wave = tid >> 6;   // 0..15
  const int lane = tid & 63;
  const int g = lane >> 4;
  const int nl = lane & 15;

  // ---- phase 0: stage x -> bf16 LDS [64][200], zero pad rows 49..63
  {
    const float* xb = x + (size_t)b * (NTOK * CDIM);
    for (int i = tid; i < NTOK * 48; i += 1024) {
      const int n = i / 48;
      const int c = (i - n * 48) * 4;
      const float4 v = *(const float4*)(xb + n * CDIM + c);
      st4bf(Xb + n * 200 + c, v.x, v.y, v.z, v.w);
    }
    if (tid < 15 * 48) {
      const int n = NTOK + tid / 48;
      const int c = (tid % 48) * 4;
      *(u64*)(Xb + n * 200 + c) = 0ull;
    }
  }
  __syncthreads();

  // ---- phase 1: QKV, 36 tasks over 16 waves; Q/K tasks also emit f32 sumsq partials
  for (int u = wave; u < 36; u += 16) {
    const int p = u / 12, o = u % 12;
    const u16* wb = w_bf + p * (CDIM * CDIM) + (o * 16 + nl) * CDIM + g * 8;
    floatx4 acc[4];
#pragma unroll
    for (int nt = 0; nt < 4; ++nt) acc[nt] = (floatx4){0.f, 0.f, 0.f, 0.f};
    if (p < 2) {
#pragma unroll
      for (int k = 0; k < 6; ++k) {
        const bf16x8 wf = *(const bf16x8*)(wb + k * 32);
#pragma unroll
        for (int nt = 0; nt < 4; ++nt) {
          const bf16x8 xk = *(const bf16x8*)(Xb + (nt * 16 + nl) * 200 + k * 32 + g * 8);
          acc[nt] = __builtin_amdgcn_mfma_f32_16x16x32_bf16(wf, xk, acc[nt], 0, 0, 0);
        }
      }
      u16* dst = (p == 0 ? Qn : Kn);
      float* np = NP + (p * 12 + o) * 64;
#pragma unroll
      for (int nt = 0; nt < 4; ++nt) {
        st4bf(dst + (nt * 16 + nl) * 200 + o * 16 + g * 4,
              acc[nt][0], acc[nt][1], acc[nt][2], acc[nt][3]);
        float s = acc[nt][0] * acc[nt][0];
        s = fmaf(acc[nt][1], acc[nt][1], s);
        s = fmaf(acc[nt][2], acc[nt][2], s);
        s = fmaf(acc[nt][3], acc[nt][3], s);
        s += __shfl_xor(s, 16);
        s += __shfl_xor(s, 32);
        if (g == 0) np[nt * 16 + nl] = s;
      }
    } else {
#pragma unroll
      for (int k = 0; k < 6; ++k) {
        const bf16x8 wf = *(const bf16x8*)(wb + k * 32);
#pragma unroll
        for (int nt = 0; nt < 4; ++nt) {
          const bf16x8 xk = *(const bf16x8*)(Xb + (nt * 16 + nl) * 200 + k * 32 + g * 8);
          acc[nt] = __builtin_amdgcn_mfma_f32_16x16x32_bf16(xk, wf, acc[nt], 0, 0, 0);
        }
      }
#pragma unroll
      for (int nt = 0; nt < 4; ++nt)
        st4bf(Vt + (o * 16 + nl) * 72 + nt * 16 + g * 4,
              acc[nt][0], acc[nt][1], acc[nt][2], acc[nt][3]);
    }
  }
  __syncthreads();

  // ---- phase 3: attention; folded norm, no max-subtraction, in-register P exchange.
  //      Waves 0-7: t={2w,2w+1} (one head); waves 8-15: t={w+8}.
  {
    const float dl = d_l[b];
    const float LOG2E = 1.442695040888963f;
    const float dl2 = dl * LOG2E;
    const int wmask = b & (NWIN - 1);
    float* nrmw = (float*)(smem + OFF_N) + wave * 128;
    const int srcA = nl + ((lane & 16) << 1);  // nl + 32*(g&1)
    const int srcB = srcA + 16;
    const bool hsel = (g >> 1) != 0;

    int t0, ntask;
    if (wave < 8) { t0 = wave * 2; ntask = 2; }
    else          { t0 = wave + 8; ntask = 1; }
    const int h = t0 >> 2;

    // combine partials -> reciprocal norms (lane = token; coalesced f32 reads)
    {
      const float kss = NP[(12 + 2 * h) * 64 + lane] + NP[(12 + 2 * h + 1) * 64 + lane];
      const float qss = NP[(2 * h) * 64 + lane] + NP[(2 * h + 1) * 64 + lane];
      nrmw[lane] = 1.f / fmaxf(sqrtf(kss), 1e-12f);
      nrmw[64 + lane] = 1.f / fmaxf(sqrtf(qss), 1e-12f);
    }

    const float tdl = temp[h] * dl2;
    bf16x8 kf[4];
#pragma unroll
    for (int rt = 0; rt < 4; ++rt)
      kf[rt] = *(const bf16x8*)(Kn + (rt * 16 + nl) * 200 + h * 32 + g * 8);

    for (int j = 0; j < ntask; ++j) {
      const int t = t0 + j;
      const int nt2 = t & 3;
      const int n = nt2 * 16 + nl;
      const int ncl = n < NTOK ? n : NTOK - 1;
      const bf16x8 qf = *(const bf16x8*)(Qn + n * 200 + h * 32 + g * 8);
      floatx4 sacc[4];
#pragma unroll
      for (int rt = 0; rt < 4; ++rt)
        sacc[rt] = __builtin_amdgcn_mfma_f32_16x16x32_bf16(kf[rt], qf, (floatx4){0.f, 0.f, 0.f, 0.f}, 0, 0, 0);
      const float qr2 = nrmw[64 + n] * tdl;
      const float* brow = bias + (h * NTOK + ncl) * NTOK;
      const float* mrow = mask + ((size_t)wmask * NTOK + ncl) * NTOK;
      float L[4][4];
#pragma unroll
      for (int rt = 0; rt < 3; ++rt) {
        const F4 b4 = *(const F4*)(brow + rt * 16 + g * 4);
        const F4 m4 = *(const F4*)(mrow + rt * 16 + g * 4);
        const F4 kr = *(const F4*)(nrmw + rt * 16 + g * 4);
#pragma unroll
        for (int r = 0; r < 4; ++r)
          L[rt][r] = fmaf(sacc[rt][r] * kr.f[r], qr2, (b4.f[r] + m4.f[r]) * dl2);
      }
      {  // rt=3: only m=48 real (g==0, r==0)
        const float lv48 = fmaf(sacc[3][0] * nrmw[48], qr2, (brow[48] + mrow[48]) * dl2);
        L[3][0] = L[3][1] = L[3][2] = L[3][3] = -1e30f;
        if (g == 0) L[3][0] = lv48;
      }
      float psum = 0.f;
#pragma unroll
      for (int rt = 0; rt < 4; ++rt)
#pragma unroll
        for (int r = 0; r < 4; ++r) {
          const float e = exp2f(L[rt][r]);
          L[rt][r] = e;
          psum += e;
        }
      psum += __shfl_xor(psum, 16);
      psum += __shfl_xor(psum, 32);
      const float rinv = 1.0f / psum;

      // in-register P -> B-fragment exchange (R3/R14-proven)
      u32 pk[4][2];
#pragma unroll
      for (int rt = 0; rt < 4; ++rt)
#pragma unroll
        for (int w2 = 0; w2 < 2; ++w2)
          pk[rt][w2] = pack2bf(L[rt][2 * w2] * rinv, L[rt][2 * w2 + 1] * rinv);
      u32 pf[2][4];
#pragma unroll
      for (int ks = 0; ks < 2; ++ks) {
        const u32 a0 = __shfl((int)pk[2 * ks][0], srcA), b0 = __shfl((int)pk[2 * ks + 1][0], srcA);
        const u32 a1 = __shfl((int)pk[2 * ks][1], srcA), b1 = __shfl((int)pk[2 * ks + 1][1], srcA);
        const u32 a2 = __shfl((int)pk[2 * ks][0], srcB), b2 = __shfl((int)pk[2 * ks + 1][0], srcB);
        const u32 a3 = __shfl((int)pk[2 * ks][1], srcB), b3 = __shfl((int)pk[2 * ks + 1][1], srcB);
        pf[ks][0] = hsel ? b0 : a0;
        pf[ks][1] = hsel ? b1 : a1;
        pf[ks][2] = hsel ? b2 : a2;
        pf[ks][3] = hsel ? b3 : a3;
      }

      floatx4 oacc[2];
      oacc[0] = (floatx4){0.f, 0.f, 0.f, 0.f};
      oacc[1] = (floatx4){0.f, 0.f, 0.f, 0.f};
#pragma unroll
      for (int ks = 0; ks < 2; ++ks) {
        const bf16x8 pfr = frag_from_words(pf[ks][0], pf[ks][1], pf[ks][2], pf[ks][3]);
#pragma unroll
        for (int dt = 0; dt < 2; ++dt) {
          const bf16x8 vf = *(const bf16x8*)(Vt + (h * 32 + dt * 16 + nl) * 72 + ks * 32 + g * 8);
          oacc[dt] = __builtin_amdgcn_mfma_f32_16x16x32_bf16(vf, pfr, oacc[dt], 0, 0, 0);
        }
      }
#pragma unroll
      for (int dt = 0; dt < 2; ++dt)
        st4bf(Xb + n * 200 + h * 32 + dt * 16 + g * 4,
              oacc[dt][0], oacc[dt][1], oacc[dt][2], oacc[dt][3]);
    }
  }
  __syncthreads();

  // ---- phase 4: out = AO @ Wp^T (out^T = Wp * AO^T), 12 tasks over 16 waves
  {
    float* outb = out + (size_t)b * (NTOK * CDIM);
    const u16* wpb = w_bf + 3 * (CDIM * CDIM);
    for (int o = wave; o < 12; o += 16) {
      const u16* wb = wpb + (o * 16 + nl) * CDIM + g * 8;
      floatx4 acc[4];
#pragma unroll
      for (int nt = 0; nt < 4; ++nt) acc[nt] = (floatx4){0.f, 0.f, 0.f, 0.f};
#pragma unroll
      for (int k = 0; k < 6; ++k) {
        const bf16x8 wf = *(const bf16x8*)(wb + k * 32);
#pragma unroll
        for (int nt = 0; nt < 4; ++nt) {
          const bf16x8 af = *(const bf16x8*)(Xb + (nt * 16 + nl) * 200 + k * 32 + g * 8);
          acc[nt] = __builtin_amdgcn_mfma_f32_16x16x32_bf16(wf, af, acc[nt], 0, 0, 0);
        }
      }
#pragma unroll
      for (int nt = 0; nt < 4; ++nt) {
        const int n = nt * 16 + nl;
        if (n < NTOK) {
          float4 v;
          v.x = acc[nt][0]; v.y = acc[nt][1]; v.z = acc[nt][2]; v.w = acc[nt][3];
          *(float4*)(outb + n * CDIM + o * 16 + g * 4) = v;
        }
      }
    }
  }
}

extern "C" void kernel_launch(void* const* d_in, const int* in_sizes, int n_in,
                              void* d_out, int out_size, void* d_ws, size_t ws_size,
                              hipStream_t stream) {
  const float* x    = (const float*)d_in[0];
  const float* mask = (const float*)d_in[1];
  const float* dl   = (const float*)d_in[2];
  const float* Wq   = (const float*)d_in[3];
  const float* Wk   = (const float*)d_in[4];
  const float* Wv   = (const float*)d_in[5];
  const float* Wp   = (const float*)d_in[6];
  const float* temp = (const float*)d_in[7];
  const float* rpb  = (const float*)d_in[8];
  const int*   rel  = (const int*)d_in[9];

  u16* w_bf = (u16*)d_ws;
  float* bias = (float*)((char*)d_ws + (size_t)4 * CDIM * CDIM * sizeof(u16));
  float* o = (float*)d_out;

  (void)hipFuncSetAttribute((const void*)wattn_main,
                            hipFuncAttributeMaxDynamicSharedMemorySize, LDS_BYTES);

  wprep<<<256, 256, 0, stream>>>(Wq, Wk, Wv, Wp, rpb, rel, w_bf, bias);
  wattn_main<<<8192, 1024, LDS_BYTES, stream>>>(x, mask, dl, temp, w_bf, bias, o);
}

// Round 19
// 527.096 us; speedup vs baseline: 2.1492x; 1.0078x over previous
//
#include <hip/hip_runtime.h>

#define NTOK 49
#define HEADS 6
#define CDIM 192
#define NWIN 4096

typedef unsigned short u16;
typedef unsigned int u32;
typedef unsigned long long u64;
typedef __attribute__((ext_vector_type(8))) __bf16 bf16x8;
typedef __attribute__((ext_vector_type(4))) float floatx4;
typedef __attribute__((ext_vector_type(4))) u32 u32x4;

struct __attribute__((aligned(4))) F4 { float f[4]; };

// LDS layout (bytes), 16-wave block (1024 thr), 1 block/CU.
// Xb/Qn/Kn: [64][256] u16, chunk-XOR swizzled (bank-conflict-free).
#define OFF_X 0         // [64][256] u16 (X, later AO)          32768
#define OFF_Q 32768     // [64][256] u16 (raw Q)                32768
#define OFF_K 65536     // [64][256] u16 (raw K)                32768
#define OFF_V 98304     // [192][72] u16  Vt[chan][tok]         27648
#define OFF_N 125952    // [16 waves][128] f32 (krec|qrec)       8192
#define OFF_NP 134144   // [2][12][64] f32 partial sumsq         6144
#define LDS_BYTES 140288

// HW bf16 convert (RNE).
__device__ __forceinline__ u16 f2bf(float f) {
  return __builtin_bit_cast(u16, (__bf16)f);
}
__device__ __forceinline__ void st4bf(u16* p, float a, float b, float c, float d) {
  u32 lo = (u32)f2bf(a) | ((u32)f2bf(b) << 16);
  u32 hi = (u32)f2bf(c) | ((u32)f2bf(d) << 16);
  u64 t = (u64)lo | ((u64)hi << 32);
  *(u64*)p = t;
}
__device__ __forceinline__ u32 pack2bf(float lo, float hi) {
  return (u32)f2bf(lo) | ((u32)f2bf(hi) << 16);
}
__device__ __forceinline__ bf16x8 frag_from_words(u32 a, u32 b, u32 c, u32 d) {
  u32x4 t = {a, b, c, d};
  return __builtin_bit_cast(bf16x8, t);
}
// chunk-XOR swizzle: u16 index for row r, u16-col c in a [64][256] region.
// XOR of 16B-chunk index with (r&7); data chunks 0..23 (multiple of 8 -> closed).
__device__ __forceinline__ int swz(int r, int c) {
  return r * 256 + ((((c >> 3) ^ (r & 7)) << 3) | (c & 7));
}

__global__ __launch_bounds__(256)
void wprep(const float* __restrict__ Wq, const float* __restrict__ Wk,
           const float* __restrict__ Wv, const float* __restrict__ Wp,
           const float* __restrict__ rpb, const int* __restrict__ rel,
           u16* __restrict__ w_bf, float* __restrict__ bias) {
  const int tid = blockIdx.x * blockDim.x + threadIdx.x;
  const int stride = gridDim.x * blockDim.x;
  for (int i = tid; i < 4 * CDIM * CDIM; i += stride) {
    const int p = i / (CDIM * CDIM), e = i % (CDIM * CDIM);
    float v = (p == 0) ? Wq[e] : (p == 1) ? Wk[e] : (p == 2) ? Wv[e] : Wp[e];
    w_bf[i] = f2bf(v);
  }
  for (int i = tid; i < HEADS * NTOK * NTOK; i += stride) {
    const int h = i / (NTOK * NTOK), nm = i % (NTOK * NTOK);
    bias[i] = rpb[rel[nm] * HEADS + h];
  }
}

// Fused window attention: R14 structure with chunk-XOR swizzled Xb/Qn/Kn
// (pure layout change; isolates whether LDS bank conflicts are on the critical path).
__global__ __launch_bounds__(1024)
void wattn_main(const float* __restrict__ x, const float* __restrict__ mask,
                const float* __restrict__ d_l, const float* __restrict__ temp,
                const u16* __restrict__ w_bf, const float* __restrict__ bias,
                float* __restrict__ out) {
  extern __shared__ __align__(16) char smem[];
  u16* Xb = (u16*)(smem + OFF_X);
  u16* Qn = (u16*)(smem + OFF_Q);
  u16* Kn = (u16*)(smem + OFF_K);
  u16* Vt = (u16*)(smem + OFF_V);
  float* NP = (float*)(smem + OFF_NP);  // [2][12][64] partial sumsq (p: 0=Q,1=K)

  const int b = blockIdx.x;
  const int tid = threadIdx.x;
  const int wave = tid >> 6;   // 0..15
  const int lane = tid & 63;
  const int g = lane >> 4;
  const int nl = lane & 15;

  // ---- phase 0: stage x -> bf16 LDS (swizzled), zero pad rows 49..63
  {
    const float* xb = x + (size_t)b * (NTOK * CDIM);
    for (int i = tid; i < NTOK * 48; i += 1024) {
      const int n = i / 48;
      const int c = (i - n * 48) * 4;
      const float4 v = *(const float4*)(xb + n * CDIM + c);
      st4bf(Xb + swz(n, c), v.x, v.y, v.z, v.w);
    }
    if (tid < 15 * 48) {
      const int n = NTOK + tid / 48;
      const int c = (tid % 48) * 4;
      *(u64*)(Xb + swz(n, c)) = 0ull;
    }
  }
  __syncthreads();

  // ---- phase 1: QKV, 36 tasks over 16 waves; Q/K tasks also emit f32 sumsq partials
  for (int u = wave; u < 36; u += 16) {
    const int p = u / 12, o = u % 12;
    const u16* wb = w_bf + p * (CDIM * CDIM) + (o * 16 + nl) * CDIM + g * 8;
    floatx4 acc[4];
#pragma unroll
    for (int nt = 0; nt < 4; ++nt) acc[nt] = (floatx4){0.f, 0.f, 0.f, 0.f};
    if (p < 2) {
#pragma unroll
      for (int k = 0; k < 6; ++k) {
        const bf16x8 wf = *(const bf16x8*)(wb + k * 32);
#pragma unroll
        for (int nt = 0; nt < 4; ++nt) {
          const bf16x8 xk = *(const bf16x8*)(Xb + swz(nt * 16 + nl, k * 32 + g * 8));
          acc[nt] = __builtin_amdgcn_mfma_f32_16x16x32_bf16(wf, xk, acc[nt], 0, 0, 0);
        }
      }
      u16* dst = (p == 0 ? Qn : Kn);
      float* np = NP + (p * 12 + o) * 64;
#pragma unroll
      for (int nt = 0; nt < 4; ++nt) {
        st4bf(dst + swz(nt * 16 + nl, o * 16 + g * 4),
              acc[nt][0], acc[nt][1], acc[nt][2], acc[nt][3]);
        float s = acc[nt][0] * acc[nt][0];
        s = fmaf(acc[nt][1], acc[nt][1], s);
        s = fmaf(acc[nt][2], acc[nt][2], s);
        s = fmaf(acc[nt][3], acc[nt][3], s);
        s += __shfl_xor(s, 16);
        s += __shfl_xor(s, 32);
        if (g == 0) np[nt * 16 + nl] = s;
      }
    } else {
#pragma unroll
      for (int k = 0; k < 6; ++k) {
        const bf16x8 wf = *(const bf16x8*)(wb + k * 32);
#pragma unroll
        for (int nt = 0; nt < 4; ++nt) {
          const bf16x8 xk = *(const bf16x8*)(Xb + swz(nt * 16 + nl, k * 32 + g * 8));
          acc[nt] = __builtin_amdgcn_mfma_f32_16x16x32_bf16(xk, wf, acc[nt], 0, 0, 0);
        }
      }
#pragma unroll
      for (int nt = 0; nt < 4; ++nt)
        st4bf(Vt + (o * 16 + nl) * 72 + nt * 16 + g * 4,
              acc[nt][0], acc[nt][1], acc[nt][2], acc[nt][3]);
    }
  }
  __syncthreads();

  // ---- phase 3: attention; folded norm, no max-subtraction, in-register P exchange.
  //      Waves 0-7: t={2w,2w+1} (one head); waves 8-15: t={w+8}.
  {
    const float dl = d_l[b];
    const float LOG2E = 1.442695040888963f;
    const float dl2 = dl * LOG2E;
    const int wmask = b & (NWIN - 1);
    float* nrmw = (float*)(smem + OFF_N) + wave * 128;
    const int srcA = nl + ((lane & 16) << 1);  // nl + 32*(g&1)
    const int srcB = srcA + 16;
    const bool hsel = (g >> 1) != 0;

    int t0, ntask;
    if (wave < 8) { t0 = wave * 2; ntask = 2; }
    else          { t0 = wave + 8; ntask = 1; }
    const int h = t0 >> 2;

    // combine partials -> reciprocal norms (lane = token; coalesced f32 reads)
    {
      const float kss = NP[(12 + 2 * h) * 64 + lane] + NP[(12 + 2 * h + 1) * 64 + lane];
      const float qss = NP[(2 * h) * 64 + lane] + NP[(2 * h + 1) * 64 + lane];
      nrmw[lane] = 1.f / fmaxf(sqrtf(kss), 1e-12f);
      nrmw[64 + lane] = 1.f / fmaxf(sqrtf(qss), 1e-12f);
    }

    const float tdl = temp[h] * dl2;
    bf16x8 kf[4];
#pragma unroll
    for (int rt = 0; rt < 4; ++rt)
      kf[rt] = *(const bf16x8*)(Kn + swz(rt * 16 + nl, h * 32 + g * 8));

    for (int j = 0; j < ntask; ++j) {
      const int t = t0 + j;
      const int nt2 = t & 3;
      const int n = nt2 * 16 + nl;
      const int ncl = n < NTOK ? n : NTOK - 1;
      const bf16x8 qf = *(const bf16x8*)(Qn + swz(n, h * 32 + g * 8));
      floatx4 sacc[4];
#pragma unroll
      for (int rt = 0; rt < 4; ++rt)
        sacc[rt] = __builtin_amdgcn_mfma_f32_16x16x32_bf16(kf[rt], qf, (floatx4){0.f, 0.f, 0.f, 0.f}, 0, 0, 0);
      const float qr2 = nrmw[64 + n] * tdl;
      const float* brow = bias + (h * NTOK + ncl) * NTOK;
      const float* mrow = mask + ((size_t)wmask * NTOK + ncl) * NTOK;
      float L[4][4];
#pragma unroll
      for (int rt = 0; rt < 3; ++rt) {
        const F4 b4 = *(const F4*)(brow + rt * 16 + g * 4);
        const F4 m4 = *(const F4*)(mrow + rt * 16 + g * 4);
        const F4 kr = *(const F4*)(nrmw + rt * 16 + g * 4);
#pragma unroll
        for (int r = 0; r < 4; ++r)
          L[rt][r] = fmaf(sacc[rt][r] * kr.f[r], qr2, (b4.f[r] + m4.f[r]) * dl2);
      }
      {  // rt=3: only m=48 real (g==0, r==0)
        const float lv48 = fmaf(sacc[3][0] * nrmw[48], qr2, (brow[48] + mrow[48]) * dl2);
        L[3][0] = L[3][1] = L[3][2] = L[3][3] = -1e30f;
        if (g == 0) L[3][0] = lv48;
      }
      float psum = 0.f;
#pragma unroll
      for (int rt = 0; rt < 4; ++rt)
#pragma unroll
        for (int r = 0; r < 4; ++r) {
          const float e = exp2f(L[rt][r]);
          L[rt][r] = e;
          psum += e;
        }
      psum += __shfl_xor(psum, 16);
      psum += __shfl_xor(psum, 32);
      const float rinv = 1.0f / psum;

      // in-register P -> B-fragment exchange (R3/R14-proven)
      u32 pk[4][2];
#pragma unroll
      for (int rt = 0; rt < 4; ++rt)
#pragma unroll
        for (int w2 = 0; w2 < 2; ++w2)
          pk[rt][w2] = pack2bf(L[rt][2 * w2] * rinv, L[rt][2 * w2 + 1] * rinv);
      u32 pf[2][4];
#pragma unroll
      for (int ks = 0; ks < 2; ++ks) {
        const u32 a0 = __shfl((int)pk[2 * ks][0], srcA), b0 = __shfl((int)pk[2 * ks + 1][0], srcA);
        const u32 a1 = __shfl((int)pk[2 * ks][1], srcA), b1 = __shfl((int)pk[2 * ks + 1][1], srcA);
        const u32 a2 = __shfl((int)pk[2 * ks][0], srcB), b2 = __shfl((int)pk[2 * ks + 1][0], srcB);
        const u32 a3 = __shfl((int)pk[2 * ks][1], srcB), b3 = __shfl((int)pk[2 * ks + 1][1], srcB);
        pf[ks][0] = hsel ? b0 : a0;
        pf[ks][1] = hsel ? b1 : a1;
        pf[ks][2] = hsel ? b2 : a2;
        pf[ks][3] = hsel ? b3 : a3;
      }

      floatx4 oacc[2];
      oacc[0] = (floatx4){0.f, 0.f, 0.f, 0.f};
      oacc[1] = (floatx4){0.f, 0.f, 0.f, 0.f};
#pragma unroll
      for (int ks = 0; ks < 2; ++ks) {
        const bf16x8 pfr = frag_from_words(pf[ks][0], pf[ks][1], pf[ks][2], pf[ks][3]);
#pragma unroll
        for (int dt = 0; dt < 2; ++dt) {
          const bf16x8 vf = *(const bf16x8*)(Vt + (h * 32 + dt * 16 + nl) * 72 + ks * 32 + g * 8);
          oacc[dt] = __builtin_amdgcn_mfma_f32_16x16x32_bf16(vf, pfr, oacc[dt], 0, 0, 0);
        }
      }
#pragma unroll
      for (int dt = 0; dt < 2; ++dt)
        st4bf(Xb + swz(n, h * 32 + dt * 16 + g * 4),
              oacc[dt][0], oacc[dt][1], oacc[dt][2], oacc[dt][3]);
    }
  }
  __syncthreads();

  // ---- phase 4: out = AO @ Wp^T (out^T = Wp * AO^T), 12 tasks over 16 waves
  {
    float* outb = out + (size_t)b * (NTOK * CDIM);
    const u16* wpb = w_bf + 3 * (CDIM * CDIM);
    for (int o = wave; o < 12; o += 16) {
      const u16* wb = wpb + (o * 16 + nl) * CDIM + g * 8;
      floatx4 acc[4];
#pragma unroll
      for (int nt = 0; nt < 4; ++nt) acc[nt] = (floatx4){0.f, 0.f, 0.f, 0.f};
#pragma unroll
      for (int k = 0; k < 6; ++k) {
        const bf16x8 wf = *(const bf16x8*)(wb + k * 32);
#pragma unroll
        for (int nt = 0; nt < 4; ++nt) {
          const bf16x8 af = *(const bf16x8*)(Xb + swz(nt * 16 + nl, k * 32 + g * 8));
          acc[nt] = __builtin_amdgcn_mfma_f32_16x16x32_bf16(wf, af, acc[nt], 0, 0, 0);
        }
      }
#pragma unroll
      for (int nt = 0; nt < 4; ++nt) {
        const int n = nt * 16 + nl;
        if (n < NTOK) {
          float4 v;
          v.x = acc[nt][0]; v.y = acc[nt][1]; v.z = acc[nt][2]; v.w = acc[nt][3];
          *(float4*)(outb + n * CDIM + o * 16 + g * 4) = v;
        }
      }
    }
  }
}

extern "C" void kernel_launch(void* const* d_in, const int* in_sizes, int n_in,
                              void* d_out, int out_size, void* d_ws, size_t ws_size,
                              hipStream_t stream) {
  const float* x    = (const float*)d_in[0];
  const float* mask = (const float*)d_in[1];
  const float* dl   = (const float*)d_in[2];
  const float* Wq   = (const float*)d_in[3];
  const float* Wk   = (const float*)d_in[4];
  const float* Wv   = (const float*)d_in[5];
  const float* Wp   = (const float*)d_in[6];
  const float* temp = (const float*)d_in[7];
  const float* rpb  = (const float*)d_in[8];
  const int*   rel  = (const int*)d_in[9];

  u16* w_bf = (u16*)d_ws;
  float* bias = (float*)((char*)d_ws + (size_t)4 * CDIM * CDIM * sizeof(u16));
  float* o = (float*)d_out;

  (void)hipFuncSetAttribute((const void*)wattn_main,
                            hipFuncAttributeMaxDynamicSharedMemorySize, LDS_BYTES);

  wprep<<<256, 256, 0, stream>>>(Wq, Wk, Wv, Wp, rpb, rel, w_bf, bias);
  wattn_main<<<8192, 1024, LDS_BYTES, stream>>>(x, mask, dl, temp, w_bf, bias, o);
}